// Round 17
// baseline (22.894 us; speedup 1.0000x reference)
//
#include <hip/hip_runtime.h>

#define IMG   512
#define NCLS  256
#define DIM   1024
#define HPW   32
#define MAGIC 0x5EEDC0DEu

typedef short bf16x8 __attribute__((ext_vector_type(8)));
typedef float f32x4  __attribute__((ext_vector_type(4)));

__device__ inline ushort bf16rne(float v) {
    unsigned u = __float_as_uint(v);
    return (ushort)((u + 0x7fffu + ((u >> 16) & 1u)) >> 16);
}

// ---------- K1: prep (64 pack + 64 hist blocks, 256 thr) ----------
// pack:  Tt2[dtile*4096 + ks*512 + g*128 + c*8 + j] = bf16(table[ks*32+g*8+j][dtile*16+c])
// hist:  Ab[grp][32][256] = bf16(count/256) for one patch-row (32 tokens)
__global__ __launch_bounds__(256)
void prep(const int* __restrict__ smap, const float* __restrict__ table,
          ushort* __restrict__ Tt2, ushort* __restrict__ Ab)
{
    __shared__ ushort   tile[16][264];
    __shared__ unsigned cnt[32 * NCLS];       // 32 KB
    const int t   = threadIdx.x;
    const int bid = blockIdx.x;

    if (bid < 64) {
        // ---- pack dtile = bid (verbatim verified R10 pack) ----
        const int dtile = bid;
        const float* src = table + (size_t)t * DIM + dtile * 16;
        #pragma unroll
        for (int q = 0; q < 4; ++q) {
            const float4 v = *reinterpret_cast<const float4*>(src + q * 4);
            tile[q * 4 + 0][t] = bf16rne(v.x);
            tile[q * 4 + 1][t] = bf16rne(v.y);
            tile[q * 4 + 2][t] = bf16rne(v.z);
            tile[q * 4 + 3][t] = bf16rne(v.w);
        }
        __syncthreads();
        const int ks   = t >> 5;
        const int g    = (t >> 3) & 3;
        const int c0   = (t & 7) * 2;
        const int cls0 = ks * 32 + g * 8;
        uint4* dst = reinterpret_cast<uint4*>(Tt2 + (size_t)dtile * 4096 + (size_t)t * 16);
        dst[0] = *reinterpret_cast<const uint4*>(&tile[c0][cls0]);
        dst[1] = *reinterpret_cast<const uint4*>(&tile[c0 + 1][cls0]);
    } else {
        // ---- histogram: one patch-row = 32 patches = 16 rows x 512 cols ----
        const int grp  = bid - 64;
        const int tok0 = grp * 32;
        const int b    = tok0 >> 10;
        const int ph   = (tok0 >> 5) & 31;

        #pragma unroll
        for (int i = t; i < 32 * NCLS; i += 256) cnt[i] = 0u;
        __syncthreads();

        const int row  = t >> 4;              // 0..15
        const int col0 = (t & 15) * 32;       // 0..480
        const int* bp = smap + ((size_t)b * IMG + (size_t)(ph * 16 + row)) * IMG + col0;
        #pragma unroll
        for (int q4 = 0; q4 < 8; ++q4) {
            const int4 q = *reinterpret_cast<const int4*>(bp + q4 * 4);
            unsigned* hp = &cnt[((col0 + q4 * 4) >> 4) * NCLS];
            atomicAdd(&hp[min(max(q.x, 0), NCLS - 1)], 1u);
            atomicAdd(&hp[min(max(q.y, 0), NCLS - 1)], 1u);
            atomicAdd(&hp[min(max(q.z, 0), NCLS - 1)], 1u);
            atomicAdd(&hp[min(max(q.w, 0), NCLS - 1)], 1u);
        }
        __syncthreads();

        ushort* ab = Ab + (size_t)grp * 8192;
        #pragma unroll
        for (int i = t; i < 8192; i += 256)
            ab[i] = (ushort)(__float_as_uint((float)cnt[i] * (1.f / 256.f)) >> 16);
    }
}

// ---------- K2: 256 blocks = (64 grp) x (4 dim-quarters); 32 tok x 256 dims each ----
__global__ __launch_bounds__(1024)
void gemm_ln(const ushort* __restrict__ Ab, const ushort* __restrict__ Tt2,
             const float* __restrict__ gamma, const float* __restrict__ beta,
             float* __restrict__ out, float* __restrict__ pstats,
             unsigned* __restrict__ flags)
{
    __shared__ ushort cntb[32][264];          // A: 32 tokens x 256 cls (padded)
    __shared__ float  red[16][2][4][4][2];    // [wave][mf][g][i][{s,s2}]
    __shared__ float  sstage[4][32][2];       // staged sibling partials
    __shared__ float  mu_s[32], rs_s[32];

    const int t    = threadIdx.x;
    const int lane = t & 63;
    const int w    = t >> 6;                  // 16 waves; wave owns dims dq*256+w*16..+16
    const int c    = lane & 15;
    const int g    = lane >> 4;

    const int grp  = blockIdx.x >> 2;
    const int dq   = blockIdx.x & 3;          // dim quarter == sincos quadrant
    const int tok0 = grp * 32;
    const int ph   = (tok0 >> 5) & 31;

    // ---- load fragment-ready A (32x256 bf16 = 16 KB) in one coalesced pass ----
    {
        const uint4 v = reinterpret_cast<const uint4*>(Ab + (size_t)grp * 8192)[t];
        const int idx = t * 8;
        *reinterpret_cast<uint4*>(&cntb[idx >> 8][idx & 255]) = v;
    }
    __syncthreads();

    // ---- MFMA K-loop: 2 M-tiles, 1 dtile/wave; B = verified Tt2 addressing ----
    f32x4 acc0 = (f32x4){0.f, 0.f, 0.f, 0.f};
    f32x4 acc1 = (f32x4){0.f, 0.f, 0.f, 0.f};
    const ushort* bt = Tt2 + (size_t)(dq * 16 + w) * 4096 + (size_t)lane * 8;
    #pragma unroll 2
    for (int ks = 0; ks < 8; ++ks) {
        const bf16x8 bf = *reinterpret_cast<const bf16x8*>(bt + ks * 512);
        const bf16x8 a0 = *reinterpret_cast<const bf16x8*>(&cntb[c][ks * 32 + g * 8]);
        const bf16x8 a1 = *reinterpret_cast<const bf16x8*>(&cntb[16 + c][ks * 32 + g * 8]);
        acc0 = __builtin_amdgcn_mfma_f32_16x16x32_bf16(a0, bf, acc0, 0, 0, 0);
        acc1 = __builtin_amdgcn_mfma_f32_16x16x32_bf16(a1, bf, acc1, 0, 0, 0);
    }

    // ---- pos-embed.  dim d = dq*256 + w*16 + c; token = mf*16 + g*4 + i ----
    {
        const float omega = exp2f((float)(w * 16 + c) * (-13.287712379549449f / 256.f));
        if (dq < 2) {                          // h-embed: same for all tokens
            float sv, cv; __sincosf((float)ph * omega, &sv, &cv);
            const float v = (dq & 1) ? cv : sv;
            #pragma unroll
            for (int i = 0; i < 4; ++i) { acc0[i] += v; acc1[i] += v; }
        } else {                               // w-embed: pw = token
            #pragma unroll
            for (int i = 0; i < 4; ++i) {
                float sv, cv;
                __sincosf((float)(g * 4 + i) * omega, &sv, &cv);
                acc0[i] += (dq & 1) ? cv : sv;
                __sincosf((float)(16 + g * 4 + i) * omega, &sv, &cv);
                acc1[i] += (dq & 1) ? cv : sv;
            }
        }
    }

    // ---- LN partials over this block's 256 dims ----
    float ls0[4], ls20[4], ls1[4], ls21[4];
    #pragma unroll
    for (int i = 0; i < 4; ++i) {
        ls0[i] = acc0[i]; ls20[i] = acc0[i] * acc0[i];
        ls1[i] = acc1[i]; ls21[i] = acc1[i] * acc1[i];
    }
    #pragma unroll
    for (int off = 1; off < 16; off <<= 1) {   // reduce over 16 c-lanes
        #pragma unroll
        for (int i = 0; i < 4; ++i) {
            ls0[i]  += __shfl_xor(ls0[i],  off, 64);
            ls20[i] += __shfl_xor(ls20[i], off, 64);
            ls1[i]  += __shfl_xor(ls1[i],  off, 64);
            ls21[i] += __shfl_xor(ls21[i], off, 64);
        }
    }
    if (c == 0) {
        #pragma unroll
        for (int i = 0; i < 4; ++i) {
            red[w][0][g][i][0] = ls0[i]; red[w][0][g][i][1] = ls20[i];
            red[w][1][g][i][0] = ls1[i]; red[w][1][g][i][1] = ls21[i];
        }
    }
    __syncthreads();

    // ---- publish partial stats (system scope), release flag ----
    if (t < 64) {
        const int token = t >> 1, which = t & 1;
        const int mf = token >> 4, gg = (token >> 2) & 3, ii = token & 3;
        float S = 0.f;
        #pragma unroll
        for (int ww = 0; ww < 16; ++ww) S += red[ww][mf][gg][ii][which];
        __hip_atomic_store(&pstats[((size_t)blockIdx.x * 32 + token) * 2 + which], S,
                           __ATOMIC_RELAXED, __HIP_MEMORY_SCOPE_SYSTEM);
    }
    __syncthreads();                           // drain all pstats stores
    if (t == 0)
        __hip_atomic_store(&flags[blockIdx.x], MAGIC,
                           __ATOMIC_RELEASE, __HIP_MEMORY_SCOPE_SYSTEM);

    // ---- acquire all 4 sibling flags, combine stats ----
    if (t < 4) {
        while (__hip_atomic_load(&flags[grp * 4 + t], __ATOMIC_ACQUIRE,
                                 __HIP_MEMORY_SCOPE_SYSTEM) != MAGIC) {}
    }
    __syncthreads();
    if (t < 256) {
        const int dq2 = t >> 6, token = (t & 63) >> 1, which = t & 1;
        sstage[dq2][token][which] =
            pstats[((size_t)(grp * 4 + dq2) * 32 + token) * 2 + which];
    }
    __syncthreads();
    if (t < 32) {
        float S = 0.f, S2 = 0.f;
        #pragma unroll
        for (int q = 0; q < 4; ++q) { S += sstage[q][t][0]; S2 += sstage[q][t][1]; }
        const float mu = S * (1.f / DIM);
        mu_s[t] = mu;
        rs_s[t] = rsqrtf(S2 * (1.f / DIM) - mu * mu + 1e-5f);
    }
    __syncthreads();

    // ---- normalize + store this block's 256 dims of its 32 tokens ----
    {
        const int d = dq * 256 + w * 16 + c;
        const float gv = gamma[d], bv = beta[d];
        #pragma unroll
        for (int i = 0; i < 4; ++i) {
            const int r0 = g * 4 + i;
            out[(size_t)(tok0 + r0) * DIM + d]      = (acc0[i] - mu_s[r0])      * rs_s[r0]      * gv + bv;
            out[(size_t)(tok0 + 16 + r0) * DIM + d] = (acc1[i] - mu_s[16 + r0]) * rs_s[16 + r0] * gv + bv;
        }
    }
}

extern "C" void kernel_launch(void* const* d_in, const int* in_sizes, int n_in,
                              void* d_out, int out_size, void* d_ws, size_t ws_size,
                              hipStream_t stream) {
    const int*   smap  = (const int*)d_in[0];
    const float* table = (const float*)d_in[1];
    const float* gamma = (const float*)d_in[2];
    const float* beta  = (const float*)d_in[3];
    float*       out   = (float*)d_out;

    const int batches = in_sizes[0] / (IMG * IMG);       // = 2
    const int tokens  = batches * HPW * HPW;             // 2048
    const int ngrp    = tokens / 32;                     // 64

    ushort*   Tt2    = (ushort*)d_ws;                              // 512 KB
    ushort*   Ab     = Tt2 + (size_t)64 * 4096;                    // 1 MB
    float*    pstats = (float*)(Ab + (size_t)ngrp * 8192);         // 64 KB
    unsigned* flags  = (unsigned*)(pstats + (size_t)ngrp * 4 * 32 * 2);

    prep<<<64 + ngrp, 256, 0, stream>>>(smap, table, Tt2, Ab);
    gemm_ln<<<ngrp * 4, 1024, 0, stream>>>(Ab, Tt2, gamma, beta, out, pstats, flags);
}